// Round 1
// baseline (3494.425 us; speedup 1.0000x reference)
//
#include <hip/hip_runtime.h>
#include <hip/hip_bf16.h>
#include <float.h>

#define N_SRC 1024
#define N_TGT 100000
#define DIM   1024
#define KNN   4

#define BM 64
#define BN 256
#define BK 32
#define NCHUNK ((N_TGT + BN - 1) / BN)   // 391

// ---------------------------------------------------------------------------
// Kernel 1: inverse norms of target rows (exact f32; source norm cancels in
// the ranking, so we never normalize the sources).
// ---------------------------------------------------------------------------
__global__ __launch_bounds__(256) void invnorm_kernel(
    const float* __restrict__ tgt, float* __restrict__ invn)
{
    int row  = blockIdx.x * 4 + (threadIdx.x >> 6);
    int lane = threadIdx.x & 63;
    if (row >= N_TGT) return;
    const float4* p = reinterpret_cast<const float4*>(tgt + (size_t)row * DIM);
    float s = 0.f;
    #pragma unroll
    for (int i = 0; i < DIM / 4 / 64; ++i) {     // 4 iters of float4
        float4 v = p[lane + i * 64];
        s += v.x * v.x + v.y * v.y + v.z * v.z + v.w * v.w;
    }
    #pragma unroll
    for (int off = 32; off > 0; off >>= 1) s += __shfl_xor(s, off);
    if (lane == 0) invn[row] = 1.0f / sqrtf(s);
}

// ---------------------------------------------------------------------------
// Kernel 2: f32 GEMM tile (BM=64 src x BN=256 tgt, BK=32) + per-chunk top-4.
// Thread (ty,tx): ty=tid>>5 in [0,8), tx=tid&31 in [0,32).
// acc[i][j] = sim(row m0+ty+8i, col n0+tx+32j).
// Row r is held by the 32 consecutive lanes with ty == r%8 (half-wave), so
// the top-4 argmax reduce uses __shfl_xor masks 1..16 (stays in the half).
// ---------------------------------------------------------------------------
__global__ __launch_bounds__(256) void gemm_topk_kernel(
    const float* __restrict__ src, const float* __restrict__ tgt,
    const float* __restrict__ invn,
    float* __restrict__ cand_val, int* __restrict__ cand_idx)
{
    __shared__ float As[BK][BM];   // 8 KB
    __shared__ float Bs[BK][BN];   // 32 KB
    const int mblk  = blockIdx.x;          // 0..15
    const int chunk = blockIdx.y;          // 0..390
    const int m0 = mblk * BM;
    const int n0 = chunk * BN;
    const int tid = threadIdx.x;
    const int tx = tid & 31;
    const int ty = tid >> 5;

    float acc[8][8];
    #pragma unroll
    for (int i = 0; i < 8; ++i)
        #pragma unroll
        for (int j = 0; j < 8; ++j) acc[i][j] = 0.f;

    for (int k0 = 0; k0 < DIM; k0 += BK) {
        // --- stage A: 64 rows x 32 k. 256 threads, 8 floats each.
        {
            int r  = tid >> 2;               // 0..63
            int c8 = (tid & 3) * 8;          // 0,8,16,24
            const float4* pa = reinterpret_cast<const float4*>(
                src + (size_t)(m0 + r) * DIM + k0 + c8);
            float4 v0 = pa[0], v1 = pa[1];
            As[c8 + 0][r] = v0.x; As[c8 + 1][r] = v0.y;
            As[c8 + 2][r] = v0.z; As[c8 + 3][r] = v0.w;
            As[c8 + 4][r] = v1.x; As[c8 + 5][r] = v1.y;
            As[c8 + 6][r] = v1.z; As[c8 + 7][r] = v1.w;
        }
        // --- stage B: 256 target rows x 32 k. One row per thread.
        {
            int col = n0 + tid;
            if (col < N_TGT) {
                const float4* pb = reinterpret_cast<const float4*>(
                    tgt + (size_t)col * DIM + k0);
                #pragma unroll
                for (int q = 0; q < 8; ++q) {
                    float4 v = pb[q];
                    Bs[q * 4 + 0][tid] = v.x; Bs[q * 4 + 1][tid] = v.y;
                    Bs[q * 4 + 2][tid] = v.z; Bs[q * 4 + 3][tid] = v.w;
                }
            } else {
                #pragma unroll
                for (int q = 0; q < BK; ++q) Bs[q][tid] = 0.f;
            }
        }
        __syncthreads();

        #pragma unroll
        for (int kk = 0; kk < BK; ++kk) {
            float a[8], b[8];
            #pragma unroll
            for (int i = 0; i < 8; ++i) a[i] = As[kk][ty + 8 * i];  // broadcast
            #pragma unroll
            for (int j = 0; j < 8; ++j) b[j] = Bs[kk][tx + 32 * j]; // stride-1
            #pragma unroll
            for (int i = 0; i < 8; ++i)
                #pragma unroll
                for (int j = 0; j < 8; ++j)
                    acc[i][j] = fmaf(a[i], b[j], acc[i][j]);
        }
        __syncthreads();
    }

    // --- apply 1/||t||, mask invalid columns
    float inv[8];
    #pragma unroll
    for (int j = 0; j < 8; ++j) {
        int c = n0 + tx + 32 * j;
        inv[j] = (c < N_TGT) ? invn[c] : 0.f;
    }
    #pragma unroll
    for (int i = 0; i < 8; ++i)
        #pragma unroll
        for (int j = 0; j < 8; ++j)
            acc[i][j] = (inv[j] > 0.f) ? acc[i][j] * inv[j] : -FLT_MAX;

    // --- per-row top-4 over this chunk's 256 columns
    #pragma unroll
    for (int i = 0; i < 8; ++i) {
        int row = m0 + ty + 8 * i;
        #pragma unroll
        for (int it = 0; it < KNN; ++it) {
            float bv = acc[i][0]; int bj = 0;
            #pragma unroll
            for (int j = 1; j < 8; ++j)
                if (acc[i][j] > bv) { bv = acc[i][j]; bj = j; }
            int bidx = n0 + tx + 32 * bj;
            #pragma unroll
            for (int off = 1; off < 32; off <<= 1) {
                float ov = __shfl_xor(bv, off);
                int   oi = __shfl_xor(bidx, off);
                if (ov > bv || (ov == bv && oi < bidx)) { bv = ov; bidx = oi; }
            }
            // invalidate winner (static indices only — no scratch)
            int txwin = (bidx - n0) & 31;
            int jwin  = (bidx - n0) >> 5;
            #pragma unroll
            for (int j = 0; j < 8; ++j)
                if (tx == txwin && j == jwin) acc[i][j] = -FLT_MAX;
            if (tx == it) {
                size_t o = ((size_t)row * NCHUNK + chunk) * KNN + it;
                cand_val[o] = bv;
                cand_idx[o] = bidx;
            }
        }
    }
}

// ---------------------------------------------------------------------------
// Kernel 3: merge 391*4 candidates per row -> exact global top-4, then
// gather original target rows and mean. One wave per source row.
// ---------------------------------------------------------------------------
__device__ __forceinline__ void ce_desc(float& v1, int& i1, float& v2, int& i2)
{
    // compare-exchange so (v1,i1) is the "greater" (tie -> lower index)
    bool sw = (v2 > v1) || (v2 == v1 && i2 < i1);
    float tv = sw ? v2 : v1; float uv = sw ? v1 : v2;
    int   ti = sw ? i2 : i1; int   ui = sw ? i1 : i2;
    v1 = tv; i1 = ti; v2 = uv; i2 = ui;
}

__global__ __launch_bounds__(256) void merge_gather_kernel(
    const float* __restrict__ tgt,
    const float* __restrict__ cand_val, const int* __restrict__ cand_idx,
    float* __restrict__ out)
{
    int wave = threadIdx.x >> 6;
    int lane = threadIdx.x & 63;
    int row  = blockIdx.x * 4 + wave;
    if (row >= N_SRC) return;

    const int NC = NCHUNK * KNN;   // 1564
    const float* cv = cand_val + (size_t)row * NC;
    const int*   ci = cand_idx + (size_t)row * NC;

    float tv[4] = { -FLT_MAX, -FLT_MAX, -FLT_MAX, -FLT_MAX };
    int   ti[4] = { 0x7fffffff, 0x7fffffff, 0x7fffffff, 0x7fffffff };

    for (int p = lane; p < NC; p += 64) {
        float v = cv[p]; int ix = ci[p];
        if (v > tv[3] || (v == tv[3] && ix < ti[3])) {
            tv[3] = v; ti[3] = ix;
            ce_desc(tv[2], ti[2], tv[3], ti[3]);
            ce_desc(tv[1], ti[1], tv[2], ti[2]);
            ce_desc(tv[0], ti[0], tv[1], ti[1]);
        }
    }
    // wave tree-merge: both lists sorted desc; reversed concat is bitonic.
    #pragma unroll
    for (int off = 1; off < 64; off <<= 1) {
        float ov[4]; int oi[4];
        #pragma unroll
        for (int q = 0; q < 4; ++q) {
            ov[q] = __shfl_xor(tv[q], off);
            oi[q] = __shfl_xor(ti[q], off);
        }
        // stage 1: top half of bitonic merge (keep maxima)
        ce_desc(tv[0], ti[0], ov[3], oi[3]);
        ce_desc(tv[1], ti[1], ov[2], oi[2]);
        ce_desc(tv[2], ti[2], ov[1], oi[1]);
        ce_desc(tv[3], ti[3], ov[0], oi[0]);
        // re-sort the surviving 4 (bitonic)
        ce_desc(tv[0], ti[0], tv[2], ti[2]);
        ce_desc(tv[1], ti[1], tv[3], ti[3]);
        ce_desc(tv[0], ti[0], tv[1], ti[1]);
        ce_desc(tv[2], ti[2], tv[3], ti[3]);
    }

    // gather 4 original target rows, mean
    const float4* p0 = reinterpret_cast<const float4*>(tgt + (size_t)ti[0] * DIM);
    const float4* p1 = reinterpret_cast<const float4*>(tgt + (size_t)ti[1] * DIM);
    const float4* p2 = reinterpret_cast<const float4*>(tgt + (size_t)ti[2] * DIM);
    const float4* p3 = reinterpret_cast<const float4*>(tgt + (size_t)ti[3] * DIM);
    float4* po = reinterpret_cast<float4*>(out + (size_t)row * DIM);
    for (int c = lane; c < DIM / 4; c += 64) {
        float4 v0 = p0[c], v1 = p1[c], v2 = p2[c], v3 = p3[c];
        float4 r;
        r.x = (v0.x + v1.x + v2.x + v3.x) * 0.25f;
        r.y = (v0.y + v1.y + v2.y + v3.y) * 0.25f;
        r.z = (v0.z + v1.z + v2.z + v3.z) * 0.25f;
        r.w = (v0.w + v1.w + v2.w + v3.w) * 0.25f;
        po[c] = r;
    }
}

// ---------------------------------------------------------------------------
extern "C" void kernel_launch(void* const* d_in, const int* in_sizes, int n_in,
                              void* d_out, int out_size, void* d_ws, size_t ws_size,
                              hipStream_t stream)
{
    const float* src = (const float*)d_in[0];
    const float* tgt = (const float*)d_in[1];
    float* out = (float*)d_out;

    // ws layout: invn [N_TGT f32] | cand_val [N_SRC*NCHUNK*4 f32] | cand_idx [same i32]
    float* invn     = (float*)d_ws;
    float* cand_val = invn + N_TGT;
    int*   cand_idx = (int*)(cand_val + (size_t)N_SRC * NCHUNK * KNN);

    invnorm_kernel<<<(N_TGT + 3) / 4, 256, 0, stream>>>(tgt, invn);

    dim3 grid(N_SRC / BM, NCHUNK);   // x = M-blocks (16) fastest -> share B panel in L2
    gemm_topk_kernel<<<grid, 256, 0, stream>>>(src, tgt, invn, cand_val, cand_idx);

    merge_gather_kernel<<<(N_SRC + 3) / 4, 256, 0, stream>>>(tgt, cand_val, cand_idx, out);
}

// Round 2
// 634.294 us; speedup vs baseline: 5.5092x; 5.5092x over previous
//
#include <hip/hip_runtime.h>
#include <hip/hip_bf16.h>
#include <float.h>

#define N_SRC 1024
#define N_TGT 100000
#define DIM   1024
#define KNN   4

// GEMM geometry: M = targets, N = sources (sources are L2-resident everywhere).
#define TB 128                       // target rows per block
#define SB 128                       // source rows per block
#define KB 32                        // k per stage
#define NK (DIM / KB)                // 32
#define SK 40                        // LDS row stride in bf16 (pad 32->40: conflict-free)
#define NMB ((N_TGT + TB - 1) / TB)  // 782 target panels
#define NSC (N_SRC / SB)             // 8 source chunks
#define NSTRIP (NMB * 2)             // 1564 64-target-row strips
#define NCAND (NSTRIP * KNN)         // 6256 candidates per source row
#define RERANK 16                    // exact-rerank candidate count

typedef __attribute__((ext_vector_type(8))) short bf16x8;
typedef __attribute__((ext_vector_type(4))) float f32x4;
typedef __attribute__((ext_vector_type(8))) unsigned short u16x8;

__device__ __forceinline__ unsigned short f2bf(float f) {
    return __builtin_bit_cast(unsigned short, __float2bfloat16(f));
}

// ---------------------------------------------------------------------------
// Kernel 1: exact f32 inverse norms of target rows.
// ---------------------------------------------------------------------------
__global__ __launch_bounds__(256) void invnorm_kernel(
    const float* __restrict__ tgt, float* __restrict__ invn)
{
    int row  = blockIdx.x * 4 + (threadIdx.x >> 6);
    int lane = threadIdx.x & 63;
    if (row >= N_TGT) return;
    const float4* p = reinterpret_cast<const float4*>(tgt + (size_t)row * DIM);
    float s = 0.f;
    #pragma unroll
    for (int i = 0; i < DIM / 4 / 64; ++i) {
        float4 v = p[lane + i * 64];
        s += v.x * v.x + v.y * v.y + v.z * v.z + v.w * v.w;
    }
    #pragma unroll
    for (int off = 32; off > 0; off >>= 1) s += __shfl_xor(s, off);
    if (lane == 0) invn[row] = 1.0f / sqrtf(s);
}

// ---------------------------------------------------------------------------
// Kernel 2: bf16 MFMA GEMM (128 tgt x 128 src, BK=32, double-buffered
// reg-staged LDS) + per-wave per-source-column top-4 over 64 target rows.
//
// MFMA 16x16x32_bf16, A = targets (row = lane&15, k = 8*(lane>>4)+j),
// B = sources^T (col = lane&15, same k layout) -> both frags are 8
// contiguous bf16 from a row-major LDS tile. C/D: col = lane&15,
// row = (lane>>4)*4 + reg  [verified m89].
// ---------------------------------------------------------------------------
__global__ __launch_bounds__(256, 3) void gemm_topk_kernel(
    const float* __restrict__ tgt, const float* __restrict__ src,
    const float* __restrict__ invn,
    float* __restrict__ cand_val, int* __restrict__ cand_idx)
{
    __shared__ __align__(16) unsigned short As[2][TB][SK];  // 20 KB
    __shared__ __align__(16) unsigned short Bs[2][SB][SK];  // 20 KB

    // XCD-aware bijective swizzle (6256 % 8 == 0): 8 consecutive logical ids
    // = all 8 source chunks of ONE target panel -> same XCD, L2-hot panel.
    const int b = blockIdx.x;
    const int logical = (b & 7) * ((NMB * NSC) / 8) + (b >> 3);
    const int mblk = logical >> 3;          // target panel [0,782)
    const int schk = logical & 7;           // source chunk [0,8)
    const int m0 = mblk * TB;
    const int c0 = schk * SB;
    const int t = threadIdx.x;
    const int lane = t & 63;
    const int w = t >> 6;
    const int wm = w >> 1, wn = w & 1;      // 2x2 wave grid, 64x64 per wave
    const int g = lane >> 4, li = lane & 15;

    f32x4 acc[4][4];
    #pragma unroll
    for (int i = 0; i < 4; ++i)
        #pragma unroll
        for (int j = 0; j < 4; ++j) acc[i][j] = (f32x4){0.f, 0.f, 0.f, 0.f};

    // staging: thread t covers row t>>1, k-half (t&1)*16 (16 floats = 4 float4)
    const int srow = t >> 1;
    const int skh  = (t & 1) * 16;
    const bool tvalid = (m0 + srow) < N_TGT;
    const float* tgp = tgt + (size_t)(m0 + srow) * DIM + skh;
    const float* srp = src + (size_t)(c0 + srow) * DIM + skh;
    unsigned short* awp = &As[0][srow][skh];
    unsigned short* bwp = &Bs[0][srow][skh];
    const int ABUF = TB * SK;   // ushort stride between buffers
    const int BBUF = SB * SK;

    float4 ra0, ra1, ra2, ra3, rb0, rb1, rb2, rb3;

    // ---- stage k-step 0 into buffer 0
    if (tvalid) {
        const float4* p = (const float4*)tgp;
        ra0 = p[0]; ra1 = p[1]; ra2 = p[2]; ra3 = p[3];
    } else {
        ra0 = ra1 = ra2 = ra3 = make_float4(0.f, 0.f, 0.f, 0.f);
    }
    {
        const float4* p = (const float4*)srp;
        rb0 = p[0]; rb1 = p[1]; rb2 = p[2]; rb3 = p[3];
    }
    {
        u16x8 va0 = {f2bf(ra0.x), f2bf(ra0.y), f2bf(ra0.z), f2bf(ra0.w),
                     f2bf(ra1.x), f2bf(ra1.y), f2bf(ra1.z), f2bf(ra1.w)};
        u16x8 va1 = {f2bf(ra2.x), f2bf(ra2.y), f2bf(ra2.z), f2bf(ra2.w),
                     f2bf(ra3.x), f2bf(ra3.y), f2bf(ra3.z), f2bf(ra3.w)};
        u16x8 vb0 = {f2bf(rb0.x), f2bf(rb0.y), f2bf(rb0.z), f2bf(rb0.w),
                     f2bf(rb1.x), f2bf(rb1.y), f2bf(rb1.z), f2bf(rb1.w)};
        u16x8 vb1 = {f2bf(rb2.x), f2bf(rb2.y), f2bf(rb2.z), f2bf(rb2.w),
                     f2bf(rb3.x), f2bf(rb3.y), f2bf(rb3.z), f2bf(rb3.w)};
        *(u16x8*)awp = va0; *(u16x8*)(awp + 8) = va1;
        *(u16x8*)bwp = vb0; *(u16x8*)(bwp + 8) = vb1;
    }
    __syncthreads();

    int cur = 0;
    for (int ks = 0; ks < NK; ++ks) {
        const bool pf = (ks + 1) < NK;
        if (pf) {                                   // issue next-tile loads early
            const int ko = (ks + 1) * KB;
            if (tvalid) {
                const float4* p = (const float4*)(tgp + ko);
                ra0 = p[0]; ra1 = p[1]; ra2 = p[2]; ra3 = p[3];
            } else {
                ra0 = ra1 = ra2 = ra3 = make_float4(0.f, 0.f, 0.f, 0.f);
            }
            const float4* p = (const float4*)(srp + ko);
            rb0 = p[0]; rb1 = p[1]; rb2 = p[2]; rb3 = p[3];
        }

        // fragment reads + 16 MFMA from buf[cur]
        {
            const unsigned short* Ab = &As[cur][0][0];
            const unsigned short* Bb = &Bs[cur][0][0];
            const int ro = g * 8;                   // k-slot byte offset /2
            bf16x8 af[4], bfr[4];
            #pragma unroll
            for (int mf = 0; mf < 4; ++mf)
                af[mf] = *(const bf16x8*)&Ab[(wm * 64 + mf * 16 + li) * SK + ro];
            #pragma unroll
            for (int nf = 0; nf < 4; ++nf)
                bfr[nf] = *(const bf16x8*)&Bb[(wn * 64 + nf * 16 + li) * SK + ro];
            #pragma unroll
            for (int mf = 0; mf < 4; ++mf)
                #pragma unroll
                for (int nf = 0; nf < 4; ++nf)
                    acc[mf][nf] = __builtin_amdgcn_mfma_f32_16x16x32_bf16(
                        af[mf], bfr[nf], acc[mf][nf], 0, 0, 0);
        }

        if (pf) {                                   // convert + write other buffer
            unsigned short* aw = awp + (cur ^ 1) * ABUF;
            unsigned short* bw = bwp + (cur ^ 1) * BBUF;
            u16x8 va0 = {f2bf(ra0.x), f2bf(ra0.y), f2bf(ra0.z), f2bf(ra0.w),
                         f2bf(ra1.x), f2bf(ra1.y), f2bf(ra1.z), f2bf(ra1.w)};
            u16x8 va1 = {f2bf(ra2.x), f2bf(ra2.y), f2bf(ra2.z), f2bf(ra2.w),
                         f2bf(ra3.x), f2bf(ra3.y), f2bf(ra3.z), f2bf(ra3.w)};
            u16x8 vb0 = {f2bf(rb0.x), f2bf(rb0.y), f2bf(rb0.z), f2bf(rb0.w),
                         f2bf(rb1.x), f2bf(rb1.y), f2bf(rb1.z), f2bf(rb1.w)};
            u16x8 vb1 = {f2bf(rb2.x), f2bf(rb2.y), f2bf(rb2.z), f2bf(rb2.w),
                         f2bf(rb3.x), f2bf(rb3.y), f2bf(rb3.z), f2bf(rb3.w)};
            *(u16x8*)aw = va0; *(u16x8*)(aw + 8) = va1;
            *(u16x8*)bw = vb0; *(u16x8*)(bw + 8) = vb1;
        }
        __syncthreads();
        cur ^= 1;
    }

    // ---- epilogue: scale by invn, per-source-column top-4 over 64 tgt rows.
    // Lane's column for frag nf: scol = c0 + wn*64 + nf*16 + li.
    // Lane's rows: m0 + wm*64 + mf*16 + g*4 + j  (16 values: mf x j).
    float invr[4][4];
    #pragma unroll
    for (int mf = 0; mf < 4; ++mf)
        #pragma unroll
        for (int j = 0; j < 4; ++j) {
            int r = m0 + wm * 64 + mf * 16 + g * 4 + j;
            invr[mf][j] = (r < N_TGT) ? invn[r] : -1.f;
        }

    const int strip = mblk * 2 + wm;
    #pragma unroll
    for (int nf = 0; nf < 4; ++nf) {
        const int scol = c0 + wn * 64 + nf * 16 + li;
        float s[4][4];
        #pragma unroll
        for (int mf = 0; mf < 4; ++mf)
            #pragma unroll
            for (int j = 0; j < 4; ++j)
                s[mf][j] = (invr[mf][j] > 0.f) ? acc[mf][nf][j] * invr[mf][j]
                                               : -FLT_MAX;
        #pragma unroll
        for (int it = 0; it < KNN; ++it) {
            // local argmax over 16 values (id = local row 0..63)
            float bv = -FLT_MAX; int bli = 0;
            #pragma unroll
            for (int mf = 0; mf < 4; ++mf)
                #pragma unroll
                for (int j = 0; j < 4; ++j) {
                    int id = mf * 16 + g * 4 + j;
                    if (s[mf][j] > bv) { bv = s[mf][j]; bli = id; }
                }
            // reduce across the 4 lane-groups holding this column
            #pragma unroll
            for (int off = 16; off < 64; off <<= 1) {
                float ov = __shfl_xor(bv, off);
                int   oi = __shfl_xor(bli, off);
                if (ov > bv || (ov == bv && oi < bli)) { bv = ov; bli = oi; }
            }
            // invalidate winner (static indices only)
            const int mfw = bli >> 4, gw = (bli >> 2) & 3, jw = bli & 3;
            if (g == gw) {
                #pragma unroll
                for (int mf = 0; mf < 4; ++mf)
                    #pragma unroll
                    for (int j = 0; j < 4; ++j)
                        if (mf == mfw && j == jw) s[mf][j] = -FLT_MAX;
            }
            if (g == it) {
                size_t o = ((size_t)scol * NSTRIP + strip) * KNN + it;
                cand_val[o] = bv;
                cand_idx[o] = m0 + wm * 64 + bli;
            }
        }
    }
}

// ---------------------------------------------------------------------------
// Kernel 3: per source row — bf16-candidate top-16, exact f32 rerank,
// top-4, gather + mean. One block (256 thr) per row.
// ---------------------------------------------------------------------------
__global__ __launch_bounds__(256) void merge_rerank_kernel(
    const float* __restrict__ src, const float* __restrict__ tgt,
    const float* __restrict__ invn,
    const float* __restrict__ cand_val, const int* __restrict__ cand_idx,
    float* __restrict__ out)
{
    __shared__ float sv[NCAND];          // 25 KB
    __shared__ float red_v[4];
    __shared__ int   red_p[4];
    __shared__ int   topi[RERANK];
    __shared__ float rsim[RERANK];
    __shared__ int   ridx[RERANK];
    __shared__ int   sel[KNN];

    const int row = blockIdx.x;
    const int t = threadIdx.x, lane = t & 63, w = t >> 6;
    const float* cv = cand_val + (size_t)row * NCAND;
    const int*   ci = cand_idx + (size_t)row * NCAND;

    for (int i = t; i < NCAND; i += 256) sv[i] = cv[i];
    __syncthreads();

    // top-16 of the bf16 candidates (selection superset only)
    for (int it = 0; it < RERANK; ++it) {
        float bv = -FLT_MAX; int bp = 0;
        for (int i = t; i < NCAND; i += 256) {
            float v = sv[i];
            if (v > bv) { bv = v; bp = i; }
        }
        #pragma unroll
        for (int off = 1; off < 64; off <<= 1) {
            float ov = __shfl_xor(bv, off);
            int   op = __shfl_xor(bp, off);
            if (ov > bv || (ov == bv && op < bp)) { bv = ov; bp = op; }
        }
        if (lane == 0) { red_v[w] = bv; red_p[w] = bp; }
        __syncthreads();
        if (t == 0) {
            float Bv = red_v[0]; int Bp = red_p[0];
            for (int q = 1; q < 4; ++q)
                if (red_v[q] > Bv || (red_v[q] == Bv && red_p[q] < Bp)) {
                    Bv = red_v[q]; Bp = red_p[q];
                }
            topi[it] = ci[Bp];
            sv[Bp] = -FLT_MAX;
        }
        __syncthreads();
    }

    // exact f32 rerank: wave w handles candidates w, w+4, w+8, w+12
    const float4* sp = (const float4*)(src + (size_t)row * DIM);
    #pragma unroll
    for (int q = 0; q < 4; ++q) {
        int cidx = topi[w + 4 * q];
        const float4* tp = (const float4*)(tgt + (size_t)cidx * DIM);
        float a = 0.f;
        #pragma unroll
        for (int p = 0; p < 4; ++p) {
            float4 x = sp[lane + 64 * p], y = tp[lane + 64 * p];
            a = fmaf(x.x, y.x, a); a = fmaf(x.y, y.y, a);
            a = fmaf(x.z, y.z, a); a = fmaf(x.w, y.w, a);
        }
        #pragma unroll
        for (int off = 1; off < 64; off <<= 1) a += __shfl_xor(a, off);
        if (lane == 0) { rsim[w + 4 * q] = a * invn[cidx]; ridx[w + 4 * q] = cidx; }
    }
    __syncthreads();

    // exact top-4 of the 16 (desc value, asc index on ties)
    if (w == 0) {
        float v = (lane < RERANK) ? rsim[lane] : -FLT_MAX;
        int  ix = (lane < RERANK) ? ridx[lane] : 0x7fffffff;
        #pragma unroll
        for (int it = 0; it < KNN; ++it) {
            float bv = v; int bix = ix;
            #pragma unroll
            for (int off = 1; off < 16; off <<= 1) {
                float ov = __shfl_xor(bv, off);
                int   oi = __shfl_xor(bix, off);
                if (ov > bv || (ov == bv && oi < bix)) { bv = ov; bix = oi; }
            }
            if (lane == 0) sel[it] = bix;
            if (ix == bix) v = -FLT_MAX;   // candidate indices are unique
        }
    }
    __syncthreads();

    // gather 4 original target rows + mean
    const float4* g0 = (const float4*)(tgt + (size_t)sel[0] * DIM);
    const float4* g1 = (const float4*)(tgt + (size_t)sel[1] * DIM);
    const float4* g2 = (const float4*)(tgt + (size_t)sel[2] * DIM);
    const float4* g3 = (const float4*)(tgt + (size_t)sel[3] * DIM);
    float4* po = (float4*)(out + (size_t)row * DIM);
    float4 v0 = g0[t], v1 = g1[t], v2 = g2[t], v3 = g3[t];
    float4 r;
    r.x = (v0.x + v1.x + v2.x + v3.x) * 0.25f;
    r.y = (v0.y + v1.y + v2.y + v3.y) * 0.25f;
    r.z = (v0.z + v1.z + v2.z + v3.z) * 0.25f;
    r.w = (v0.w + v1.w + v2.w + v3.w) * 0.25f;
    po[t] = r;
}

// ---------------------------------------------------------------------------
extern "C" void kernel_launch(void* const* d_in, const int* in_sizes, int n_in,
                              void* d_out, int out_size, void* d_ws, size_t ws_size,
                              hipStream_t stream)
{
    const float* src = (const float*)d_in[0];
    const float* tgt = (const float*)d_in[1];
    float* out = (float*)d_out;

    // ws: invn [100096 f32] | cand_val [1024*6256 f32] | cand_idx [same i32]  (~51.6 MB)
    float* invn     = (float*)d_ws;
    float* cand_val = invn + 100096;
    int*   cand_idx = (int*)(cand_val + (size_t)N_SRC * NCAND);

    invnorm_kernel<<<(N_TGT + 3) / 4, 256, 0, stream>>>(tgt, invn);

    gemm_topk_kernel<<<NMB * NSC, 256, 0, stream>>>(tgt, src, invn,
                                                    cand_val, cand_idx);

    merge_rerank_kernel<<<N_SRC, 256, 0, stream>>>(src, tgt, invn,
                                                   cand_val, cand_idx, out);
}

// Round 3
// 578.568 us; speedup vs baseline: 6.0398x; 1.0963x over previous
//
#include <hip/hip_runtime.h>
#include <hip/hip_bf16.h>
#include <float.h>

#define N_SRC 1024
#define N_TGT 100000
#define DIM   1024
#define KNN   4

// GEMM geometry: M = targets, N = sources.
#define TB 128
#define SB 128
#define KB 32
#define NK (DIM / KB)                // 32
#define NMB ((N_TGT + TB - 1) / TB)  // 782 target panels
#define NSC (N_SRC / SB)             // 8 source chunks
#define NSTRIP (NMB * 2)             // 1564
#define NCAND (NSTRIP * KNN)         // 6256 candidates per source row
#define RERANK 16

typedef __attribute__((ext_vector_type(8))) short bf16x8;
typedef __attribute__((ext_vector_type(4))) float f32x4;
typedef __attribute__((ext_vector_type(4))) unsigned int u32x4;

// bf16 truncation pack: one v_perm_b32 for two floats.
// result = (hi16(b) << 16) | hi16(a)   [a = lower k index]
__device__ __forceinline__ unsigned int pack_trunc(float a, float b) {
    return __builtin_amdgcn_perm(__builtin_bit_cast(unsigned int, b),
                                 __builtin_bit_cast(unsigned int, a),
                                 0x07060302u);
}

__device__ __forceinline__ void gload16(const void* gp, void* lp) {
    __builtin_amdgcn_global_load_lds(
        (const __attribute__((address_space(1))) void*)gp,
        (__attribute__((address_space(3))) void*)lp, 16, 0, 0);
}

// ---------------------------------------------------------------------------
// Kernel 1: convert sources f32 -> bf16 into ws, tiled [ks][1024 rows][64 B]
// with the LDS slot swizzle PRE-APPLIED: position slot holds content
// slot ^ ((row>>1)&3). GEMM then global_load_lds's it linearly.
// ---------------------------------------------------------------------------
__global__ __launch_bounds__(256) void convert_src_kernel(
    const float* __restrict__ src, unsigned int* __restrict__ srcws)
{
    int gid  = blockIdx.x * 256 + threadIdx.x;   // one 16B chunk; 131072 total
    int ks   = gid >> 12;
    int rem  = gid & 4095;
    int row  = rem >> 2;
    int slot = rem & 3;
    int kin  = ks * KB + ((slot ^ ((row >> 1) & 3)) << 3);
    const float4* p = (const float4*)(src + (size_t)row * DIM + kin);
    float4 a = p[0], b = p[1];
    u32x4 o = { pack_trunc(a.x, a.y), pack_trunc(a.z, a.w),
                pack_trunc(b.x, b.y), pack_trunc(b.z, b.w) };
    ((u32x4*)srcws)[gid] = o;
}

// ---------------------------------------------------------------------------
// Kernel 2: bf16 MFMA GEMM + per-wave per-source-column top-4 + in-block
// target norms. A staged f32->perm-pack->swizzled ds_write; B staged via
// global_load_lds from the pre-swizzled srcws. Linear [128][32]-ushort LDS
// tiles; swizzle slot ^= (row>>1)&3 on both sides (2-way max = free).
// ---------------------------------------------------------------------------
__global__ __launch_bounds__(256, 3) void gemm_topk_kernel(
    const float* __restrict__ tgt, const void* __restrict__ srcws,
    float* __restrict__ cand_val, int* __restrict__ cand_idx)
{
    __shared__ __align__(16) unsigned short As[2][TB][KB];  // 16 KB
    __shared__ __align__(16) unsigned short Bs[2][SB][KB];  // 16 KB
    __shared__ float nsq_sh[256];
    __shared__ float invn_sh[TB];

    const int b = blockIdx.x;
    const int logical = (b & 7) * ((NMB * NSC) / 8) + (b >> 3);
    const int mblk = logical >> 3;
    const int schk = logical & 7;
    const int m0 = mblk * TB;
    const int c0 = schk * SB;
    const int t = threadIdx.x;
    const int lane = t & 63;
    const int w = t >> 6;
    const int wm = w >> 1, wn = w & 1;
    const int g = lane >> 4, li = lane & 15;

    // A staging role: thread t -> row r, k-half h (lanes 0..63 = rows 0..63:
    // write phases are conflict-free with the slot swizzle).
    const int r  = t & 127;
    const int h  = t >> 7;
    const int sr = (r >> 1) & 3;
    const int wslot0 = (2 * h) ^ sr;
    const int wslot1 = (2 * h + 1) ^ sr;
    const bool tvalid = (m0 + r) < N_TGT;
    const float* tgp = tgt + (size_t)(m0 + r) * DIM + h * 16;

    // B gload role: wave w fills LDS rows [w*32, w*32+32) via 2 instrs.
    const size_t bofs = ((size_t)(c0 + w * 32) * 64) + (size_t)lane * 16;
    const char* srcb = (const char*)srcws;

    f32x4 acc[4][4];
    #pragma unroll
    for (int i = 0; i < 4; ++i)
        #pragma unroll
        for (int j = 0; j < 4; ++j) acc[i][j] = (f32x4){0.f, 0.f, 0.f, 0.f};

    float nsq = 0.f;
    float4 ra0, ra1, ra2, ra3;

    #define LOAD_A(ks_) do {                                                  \
        if (tvalid) {                                                         \
            const float4* p_ = (const float4*)(tgp + (ks_) * KB);             \
            ra0 = p_[0]; ra1 = p_[1]; ra2 = p_[2]; ra3 = p_[3];               \
        } else {                                                              \
            ra0 = ra1 = ra2 = ra3 = make_float4(0.f, 0.f, 0.f, 0.f);          \
        }                                                                     \
    } while (0)

    #define STAGE_B(buf_, ks_) do {                                           \
        const char* gp_ = srcb + (size_t)(ks_) * 65536 + bofs;                \
        gload16(gp_,        &Bs[buf_][w * 32][0]);                            \
        gload16(gp_ + 1024, &Bs[buf_][w * 32 + 16][0]);                       \
    } while (0)

    #define PACK_WRITE_A(buf_) do {                                           \
        nsq += ra0.x*ra0.x + ra0.y*ra0.y + ra0.z*ra0.z + ra0.w*ra0.w          \
             + ra1.x*ra1.x + ra1.y*ra1.y + ra1.z*ra1.z + ra1.w*ra1.w          \
             + ra2.x*ra2.x + ra2.y*ra2.y + ra2.z*ra2.z + ra2.w*ra2.w          \
             + ra3.x*ra3.x + ra3.y*ra3.y + ra3.z*ra3.z + ra3.w*ra3.w;         \
        u32x4 p0_ = { pack_trunc(ra0.x, ra0.y), pack_trunc(ra0.z, ra0.w),     \
                      pack_trunc(ra1.x, ra1.y), pack_trunc(ra1.z, ra1.w) };   \
        u32x4 p1_ = { pack_trunc(ra2.x, ra2.y), pack_trunc(ra2.z, ra2.w),     \
                      pack_trunc(ra3.x, ra3.y), pack_trunc(ra3.z, ra3.w) };   \
        *(u32x4*)&As[buf_][r][wslot0 * 8] = p0_;                              \
        *(u32x4*)&As[buf_][r][wslot1 * 8] = p1_;                              \
    } while (0)

    // ---- prologue: stage K-step 0 into buffer 0
    STAGE_B(0, 0);
    LOAD_A(0);
    PACK_WRITE_A(0);
    __syncthreads();

    const int sw = (li >> 1) & 3;     // frag-read slot swizzle
    const int ro = (g ^ sw) * 8;

    int cur = 0;
    for (int ks = 0; ks < NK; ++ks) {
        const bool pf = (ks + 1) < NK;
        if (pf) {
            STAGE_B(cur ^ 1, ks + 1);
            LOAD_A(ks + 1);
        }

        bf16x8 af[4], bfr[4];
        #pragma unroll
        for (int mf = 0; mf < 4; ++mf)
            af[mf] = *(const bf16x8*)&As[cur][wm * 64 + mf * 16 + li][ro];
        #pragma unroll
        for (int nf = 0; nf < 4; ++nf)
            bfr[nf] = *(const bf16x8*)&Bs[cur][wn * 64 + nf * 16 + li][ro];
        #pragma unroll
        for (int mf = 0; mf < 4; ++mf)
            #pragma unroll
            for (int nf = 0; nf < 4; ++nf)
                acc[mf][nf] = __builtin_amdgcn_mfma_f32_16x16x32_bf16(
                    af[mf], bfr[nf], acc[mf][nf], 0, 0, 0);

        if (pf) PACK_WRITE_A(cur ^ 1);
        __syncthreads();
        cur ^= 1;
    }

    // ---- in-block target inverse norms (exact f32 from original values)
    nsq_sh[t] = nsq;
    __syncthreads();
    if (t < TB) {
        float s = nsq_sh[t] + nsq_sh[t + 128];
        invn_sh[t] = ((m0 + t) < N_TGT) ? 1.0f / sqrtf(s) : -1.0f;
    }
    __syncthreads();

    // ---- epilogue: scale, per-source-column top-4 over this wave's 64 rows
    float invr[4][4];
    #pragma unroll
    for (int mf = 0; mf < 4; ++mf)
        #pragma unroll
        for (int j = 0; j < 4; ++j)
            invr[mf][j] = invn_sh[wm * 64 + mf * 16 + g * 4 + j];

    const int strip = mblk * 2 + wm;
    #pragma unroll
    for (int nf = 0; nf < 4; ++nf) {
        const int scol = c0 + wn * 64 + nf * 16 + li;
        float s[4][4];
        #pragma unroll
        for (int mf = 0; mf < 4; ++mf)
            #pragma unroll
            for (int j = 0; j < 4; ++j)
                s[mf][j] = (invr[mf][j] > 0.f) ? acc[mf][nf][j] * invr[mf][j]
                                               : -FLT_MAX;
        #pragma unroll
        for (int it = 0; it < KNN; ++it) {
            float bv = -FLT_MAX; int bli = 0;
            #pragma unroll
            for (int mf = 0; mf < 4; ++mf)
                #pragma unroll
                for (int j = 0; j < 4; ++j) {
                    int id = mf * 16 + g * 4 + j;
                    if (s[mf][j] > bv) { bv = s[mf][j]; bli = id; }
                }
            #pragma unroll
            for (int off = 16; off < 64; off <<= 1) {
                float ov = __shfl_xor(bv, off);
                int   oi = __shfl_xor(bli, off);
                if (ov > bv || (ov == bv && oi < bli)) { bv = ov; bli = oi; }
            }
            const int mfw = bli >> 4, gw = (bli >> 2) & 3, jw = bli & 3;
            if (g == gw) {
                #pragma unroll
                for (int mf = 0; mf < 4; ++mf)
                    #pragma unroll
                    for (int j = 0; j < 4; ++j)
                        if (mf == mfw && j == jw) s[mf][j] = -FLT_MAX;
            }
            if (g == it) {
                size_t o = ((size_t)scol * NSTRIP + strip) * KNN + it;
                cand_val[o] = bv;
                cand_idx[o] = m0 + wm * 64 + bli;
            }
        }
    }
}

// ---------------------------------------------------------------------------
// Kernel 3: per source row — candidate top-16, exact f32 rerank (computing
// exact target norms from the rows it reads), top-4, gather + mean.
// ---------------------------------------------------------------------------
__global__ __launch_bounds__(256) void merge_rerank_kernel(
    const float* __restrict__ src, const float* __restrict__ tgt,
    const float* __restrict__ cand_val, const int* __restrict__ cand_idx,
    float* __restrict__ out)
{
    __shared__ float sv[NCAND];          // 25 KB
    __shared__ float red_v[4];
    __shared__ int   red_p[4];
    __shared__ int   topi[RERANK];
    __shared__ float rsim[RERANK];
    __shared__ int   ridx[RERANK];
    __shared__ int   sel[KNN];

    const int row = blockIdx.x;
    const int t = threadIdx.x, lane = t & 63, w = t >> 6;
    const float* cv = cand_val + (size_t)row * NCAND;
    const int*   ci = cand_idx + (size_t)row * NCAND;

    for (int i = t; i < NCAND; i += 256) sv[i] = cv[i];
    __syncthreads();

    for (int it = 0; it < RERANK; ++it) {
        float bv = -FLT_MAX; int bp = 0;
        for (int i = t; i < NCAND; i += 256) {
            float v = sv[i];
            if (v > bv) { bv = v; bp = i; }
        }
        #pragma unroll
        for (int off = 1; off < 64; off <<= 1) {
            float ov = __shfl_xor(bv, off);
            int   op = __shfl_xor(bp, off);
            if (ov > bv || (ov == bv && op < bp)) { bv = ov; bp = op; }
        }
        if (lane == 0) { red_v[w] = bv; red_p[w] = bp; }
        __syncthreads();
        if (t == 0) {
            float Bv = red_v[0]; int Bp = red_p[0];
            for (int q = 1; q < 4; ++q)
                if (red_v[q] > Bv || (red_v[q] == Bv && red_p[q] < Bp)) {
                    Bv = red_v[q]; Bp = red_p[q];
                }
            topi[it] = ci[Bp];
            sv[Bp] = -FLT_MAX;
        }
        __syncthreads();
    }

    // exact f32 rerank: dot AND target norm from the same row read
    const float4* sp = (const float4*)(src + (size_t)row * DIM);
    #pragma unroll
    for (int q = 0; q < 4; ++q) {
        int cidx = topi[w + 4 * q];
        const float4* tp = (const float4*)(tgt + (size_t)cidx * DIM);
        float a = 0.f, nn = 0.f;
        #pragma unroll
        for (int p = 0; p < 4; ++p) {
            float4 x = sp[lane + 64 * p], y = tp[lane + 64 * p];
            a  = fmaf(x.x, y.x, a);  a  = fmaf(x.y, y.y, a);
            a  = fmaf(x.z, y.z, a);  a  = fmaf(x.w, y.w, a);
            nn = fmaf(y.x, y.x, nn); nn = fmaf(y.y, y.y, nn);
            nn = fmaf(y.z, y.z, nn); nn = fmaf(y.w, y.w, nn);
        }
        #pragma unroll
        for (int off = 1; off < 64; off <<= 1) {
            a  += __shfl_xor(a, off);
            nn += __shfl_xor(nn, off);
        }
        if (lane == 0) { rsim[w + 4 * q] = a / sqrtf(nn); ridx[w + 4 * q] = cidx; }
    }
    __syncthreads();

    if (w == 0) {
        float v = (lane < RERANK) ? rsim[lane] : -FLT_MAX;
        int  ix = (lane < RERANK) ? ridx[lane] : 0x7fffffff;
        #pragma unroll
        for (int it = 0; it < KNN; ++it) {
            float bv = v; int bix = ix;
            #pragma unroll
            for (int off = 1; off < 16; off <<= 1) {
                float ov = __shfl_xor(bv, off);
                int   oi = __shfl_xor(bix, off);
                if (ov > bv || (ov == bv && oi < bix)) { bv = ov; bix = oi; }
            }
            if (lane == 0) sel[it] = bix;
            if (ix == bix) v = -FLT_MAX;
        }
    }
    __syncthreads();

    const float4* g0 = (const float4*)(tgt + (size_t)sel[0] * DIM);
    const float4* g1 = (const float4*)(tgt + (size_t)sel[1] * DIM);
    const float4* g2 = (const float4*)(tgt + (size_t)sel[2] * DIM);
    const float4* g3 = (const float4*)(tgt + (size_t)sel[3] * DIM);
    float4* po = (float4*)(out + (size_t)row * DIM);
    float4 v0 = g0[t], v1 = g1[t], v2 = g2[t], v3 = g3[t];
    float4 rr;
    rr.x = (v0.x + v1.x + v2.x + v3.x) * 0.25f;
    rr.y = (v0.y + v1.y + v2.y + v3.y) * 0.25f;
    rr.z = (v0.z + v1.z + v2.z + v3.z) * 0.25f;
    rr.w = (v0.w + v1.w + v2.w + v3.w) * 0.25f;
    po[t] = rr;
}

// ---------------------------------------------------------------------------
extern "C" void kernel_launch(void* const* d_in, const int* in_sizes, int n_in,
                              void* d_out, int out_size, void* d_ws, size_t ws_size,
                              hipStream_t stream)
{
    const float* src = (const float*)d_in[0];
    const float* tgt = (const float*)d_in[1];
    float* out = (float*)d_out;

    // ws: srcws bf16 tiled/pre-swizzled [2 MB] | cand_val [25.6 MB] | cand_idx [25.6 MB]
    unsigned int* srcws = (unsigned int*)d_ws;
    float* cand_val = (float*)((char*)d_ws + (2u << 20));
    int*   cand_idx = (int*)(cand_val + (size_t)N_SRC * NCAND);

    convert_src_kernel<<<512, 256, 0, stream>>>(src, srcws);

    gemm_topk_kernel<<<NMB * NSC, 256, 0, stream>>>(tgt, srcws,
                                                    cand_val, cand_idx);

    merge_rerank_kernel<<<N_SRC, 256, 0, stream>>>(src, tgt,
                                                   cand_val, cand_idx, out);
}